// Round 2
// baseline (468.087 us; speedup 1.0000x reference)
//
#include <hip/hip_runtime.h>

// Discounted cumulative return y[t] = r[t] + a[t]*y[t+1], a[t]=terminal[t]?0:0.99
// Round 9 (= Round 8 + compile fix): single-pass decoupled-lookback scan.
// The former K1/K2 pair is fused: each block publishes its affine aggregate
// (A,B) with an agent-scope release flag, then wave 0 window-composes
// predecessor aggregates (ticket order makes this deadlock-free), with an
// EXACT early-exit when the accumulated A zeroes (any terminal in a tile
// zeroes its A, p~=0.9997/tile). The sparse tail correction (past the block's
// last terminal) runs in-block. Main output stores are nontemporal (via a
// native clang ext_vector_type — HIP float4 is a class and is rejected by
// __builtin_nontemporal_store).
//
// Affine F(x)=A*x+B maps y[hi+1]->y[lo]; compose outer = lower indices:
// (A1,B1)o(A2,B2) = (A1*A2, A1*B2+B1).

constexpr int   TPB   = 256;
constexpr int   IPTC  = 8;               // elems per thread per chunk
constexpr int   NCH   = 4;               // chunks per block (pipelined)
constexpr int   CHUNK = TPB * IPTC;      // 2048
constexpr int   TILE  = CHUNK * NCH;     // 8192 elems per block
constexpr float DISC  = 0.99f;
constexpr float L2DISC = -0.0144995696f; // log2(0.99)

#define SCOPE_AGENT __HIP_MEMORY_SCOPE_AGENT

typedef float vf4 __attribute__((ext_vector_type(4)));   // nontemporal-storable

// Inclusive wave SUFFIX scan: lane l ends with F_l o F_{l+1} o ... o F_63.
__device__ __forceinline__ void wave_suffix_scan(float& A, float& B, int lane) {
    #pragma unroll
    for (int off = 1; off < 64; off <<= 1) {
        float oA = __shfl_down(A, off, 64);
        float oB = __shfl_down(B, off, 64);
        if (lane + off < 64) { B = A * oB + B; A = A * oA; }
    }
}

__global__ __launch_bounds__(TPB) void k_scan(
        const int* __restrict__ term, const float* __restrict__ rew,
        float* __restrict__ out,
        int* __restrict__ flags, int* __restrict__ ticket,
        unsigned long long* __restrict__ AB, float* __restrict__ Incl,
        int nB, long long T) {
    __shared__ float2 sWA[TPB / 64];
    __shared__ int    sLast[TPB / 64];
    __shared__ int    sVb;
    __shared__ float  sYin;

    const int t = threadIdx.x;
    const int lane = t & 63, wav = t >> 6;

    if (t == 0) sVb = atomicAdd(ticket, 1);
    __syncthreads();
    const int vb = sVb;                  // virtual id in scheduling order
    const int b  = nB - 1 - vb;          // vb=0 -> highest tile (scan is a suffix)
    const long long lo = (long long)b * TILE;
    const bool fastblk = (lo + TILE <= T);

    float At = 1.f, Bt = 0.f;   // block aggregate over processed (higher) chunks
    int   lt = -1;              // last terminal global index in block

    if (fastblk) {
        float4 bR[2][IPTC / 4];
        int4   bT[2][IPTC / 4];

        // prefetch highest chunk
        {
            const long long base = lo + (long long)(NCH - 1) * CHUNK
                                      + (long long)t * IPTC;
            const float4* rp = (const float4*)(rew + base);
            const int4*   tp = (const int4*)(term + base);
            #pragma unroll
            for (int q = 0; q < IPTC / 4; ++q) {
                bR[(NCH - 1) & 1][q] = rp[q];
                bT[(NCH - 1) & 1][q] = tp[q];
            }
        }

        #pragma unroll
        for (int c = NCH - 1; c >= 0; --c) {
            // issue next (lower) chunk's loads before computing this one
            if (c > 0) {
                const long long nbase = lo + (long long)(c - 1) * CHUNK
                                           + (long long)t * IPTC;
                const float4* rp = (const float4*)(rew + nbase);
                const int4*   tp = (const int4*)(term + nbase);
                #pragma unroll
                for (int q = 0; q < IPTC / 4; ++q) {
                    bR[(c - 1) & 1][q] = rp[q];
                    bT[(c - 1) & 1][q] = tp[q];
                }
            }
            const int p = c & 1;
            const long long base = lo + (long long)c * CHUNK + (long long)t * IPTC;

            float r[IPTC];
            unsigned mask = 0;
            #pragma unroll
            for (int q = 0; q < IPTC / 4; ++q) {
                float4 rv = bR[p][q];
                int4   tv = bT[p][q];
                r[4*q+0] = rv.x; r[4*q+1] = rv.y; r[4*q+2] = rv.z; r[4*q+3] = rv.w;
                mask |= (tv.x ? 1u : 0u) << (4*q+0);
                mask |= (tv.y ? 1u : 0u) << (4*q+1);
                mask |= (tv.z ? 1u : 0u) << (4*q+2);
                mask |= (tv.w ? 1u : 0u) << (4*q+3);
            }

            // thread-local compose, high->low
            float A = 1.f, B = 0.f;
            #pragma unroll
            for (int k = IPTC - 1; k >= 0; --k) {
                float ak = ((mask >> k) & 1u) ? 0.f : DISC;
                B = ak * B + r[k]; A = ak * A;
            }

            float IA = A, IB = B;
            wave_suffix_scan(IA, IB, lane);

            int myLast = mask ? (int)(base + (31 - __clz(mask))) : -1;
            #pragma unroll
            for (int off = 32; off > 0; off >>= 1)
                myLast = max(myLast, __shfl_down(myLast, off, 64));

            if (lane == 0) { sWA[wav] = make_float2(IA, IB); sLast[wav] = myLast; }
            __syncthreads();

            // chunk aggregate + exclusives (all threads, redundant & cheap)
            float2 g = sWA[0];
            int cl = sLast[0];
            #pragma unroll
            for (int w = 1; w < TPB / 64; ++w) {
                float2 h = sWA[w];
                g.y = g.x * h.y + g.y; g.x = g.x * h.x;
                cl = max(cl, sLast[w]);
            }
            float EWA = 1.f, EWB = 0.f;
            #pragma unroll
            for (int w = 0; w < TPB / 64; ++w)
                if (w > wav) { float2 h = sWA[w]; EWB = EWA*h.y + EWB; EWA = EWA*h.x; }

            float EA = __shfl_down(IA, 1, 64);
            float EB = __shfl_down(IB, 1, 64);
            if (lane == 63) { EA = 1.f; EB = 0.f; }

            const float Yc = Bt;              // y entering this chunk from above
            float y = EA * (EWA * Yc + EWB) + EB;

            #pragma unroll
            for (int k = IPTC - 1; k >= 0; --k) {
                float ak = ((mask >> k) & 1u) ? 0.f : DISC;
                y = ak * y + r[k]; r[k] = y;
            }

            vf4* op = (vf4*)(out + base);
            #pragma unroll
            for (int q = 0; q < IPTC / 4; ++q) {
                vf4 v = { r[4*q+0], r[4*q+1], r[4*q+2], r[4*q+3] };
                __builtin_nontemporal_store(v, op + q);
            }

            // fold chunk into block aggregate: F_new = F_c o F_prev
            Bt = g.x * Bt + g.y;
            At = g.x * At;
            lt = max(lt, cl);
            __syncthreads();   // protect sWA/sLast reuse next chunk
        }
    } else {
        // guarded tail block (only the highest tile when T % TILE != 0; vb==0)
        for (int c = NCH - 1; c >= 0; --c) {
            const long long base = lo + (long long)c * CHUNK + (long long)t * IPTC;
            float r[IPTC];
            unsigned mask = 0;
            #pragma unroll
            for (int k = 0; k < IPTC; ++k) {
                long long i = base + k;
                if (i < T) { r[k] = rew[i]; mask |= (term[i] ? 1u : 0u) << k; }
                else       { r[k] = 0.f; }
            }
            float A = 1.f, B = 0.f;
            #pragma unroll
            for (int k = IPTC - 1; k >= 0; --k) {
                float ak = ((mask >> k) & 1u) ? 0.f : DISC;
                if (base + k >= T) ak = 1.f;
                B = ak * B + r[k]; A = ak * A;
            }
            float IA = A, IB = B;
            wave_suffix_scan(IA, IB, lane);

            int myLast = mask ? (int)(base + (31 - __clz(mask))) : -1;
            #pragma unroll
            for (int off = 32; off > 0; off >>= 1)
                myLast = max(myLast, __shfl_down(myLast, off, 64));

            if (lane == 0) { sWA[wav] = make_float2(IA, IB); sLast[wav] = myLast; }
            __syncthreads();

            float2 g = sWA[0];
            int cl = sLast[0];
            #pragma unroll
            for (int w = 1; w < TPB / 64; ++w) {
                float2 h = sWA[w];
                g.y = g.x * h.y + g.y; g.x = g.x * h.x;
                cl = max(cl, sLast[w]);
            }
            float EWA = 1.f, EWB = 0.f;
            #pragma unroll
            for (int w = 0; w < TPB / 64; ++w)
                if (w > wav) { float2 h = sWA[w]; EWB = EWA*h.y + EWB; EWA = EWA*h.x; }

            float EA = __shfl_down(IA, 1, 64);
            float EB = __shfl_down(IB, 1, 64);
            if (lane == 63) { EA = 1.f; EB = 0.f; }

            const float Yc = Bt;
            float y = EA * (EWA * Yc + EWB) + EB;

            #pragma unroll
            for (int k = IPTC - 1; k >= 0; --k) {
                float ak = ((mask >> k) & 1u) ? 0.f : DISC;
                if (base + k >= T) ak = 1.f;
                y = ak * y + r[k]; r[k] = y;
            }
            #pragma unroll
            for (int k = 0; k < IPTC; ++k) {
                long long i = base + k;
                if (i < T) out[i] = r[k];
            }

            Bt = g.x * Bt + g.y;
            At = g.x * At;
            lt = max(lt, cl);
            __syncthreads();
        }
    }

    // ---- publish this block's aggregate (flag: 0=empty, 1=agg, 2=agg+prefix) ----
    if (t == 0) {
        union { float2 f; unsigned long long u; } c;
        c.f = make_float2(At, Bt);
        __hip_atomic_store(&AB[vb], c.u, __ATOMIC_RELAXED, SCOPE_AGENT);
        __hip_atomic_store(&flags[vb], 1, __ATOMIC_RELEASE, SCOPE_AGENT);
    }

    // ---- decoupled lookback over lower tickets (higher-t tiles), wave 0 ----
    if (wav == 0) {
        float yin = 0.f;
        float Ca = 1.f, Cb = 0.f;   // y_in = Ca * (suffix beyond window) + Cb
        int look = vb - 1;
        for (;;) {
            if (look < 0 || Ca == 0.f) { yin = Cb; break; }  // Ca==0: exact early exit
            const int p = look - lane;          // lane 0 = nearest predecessor (outermost)
            int f = 0;
            if (p >= 0) f = __hip_atomic_load(&flags[p], __ATOMIC_ACQUIRE, SCOPE_AGENT);
            const unsigned long long balP = __ballot(f == 2);
            const unsigned long long balA = __ballot(f != 0);
            const unsigned long long vmask =
                (look >= 63) ? ~0ull : ((1ull << (look + 1)) - 1ull);
            const unsigned long long prefAvail = balP & vmask;
            bool consumed = false;
            if (prefAvail) {
                const int lp = (int)__ffsll((long long)prefAvail) - 1;
                const unsigned long long need = (1ull << lp) - 1ull;
                if ((balA & need) == need) {     // aggs before nearest prefix all ready
                    float a = 1.f, bv = 0.f;
                    if (lane < lp) {
                        union { unsigned long long u; float2 f2; } c;
                        c.u = __hip_atomic_load(&AB[p], __ATOMIC_RELAXED, SCOPE_AGENT);
                        a = c.f2.x; bv = c.f2.y;
                    } else if (lane == lp) {
                        a = 0.f;
                        bv = __hip_atomic_load(&Incl[p], __ATOMIC_RELAXED, SCOPE_AGENT);
                    }
                    wave_suffix_scan(a, bv, lane);
                    bv = __shfl(bv, 0, 64);
                    yin = Ca * bv + Cb;
                    break;
                }
            }
            if ((balA & vmask) == vmask) {       // full window of aggregates ready
                float a = 1.f, bv = 0.f;
                if (p >= 0) {
                    union { unsigned long long u; float2 f2; } c;
                    c.u = __hip_atomic_load(&AB[p], __ATOMIC_RELAXED, SCOPE_AGENT);
                    a = c.f2.x; bv = c.f2.y;
                }
                wave_suffix_scan(a, bv, lane);
                const float wA = __shfl(a, 0, 64);
                const float wB = __shfl(bv, 0, 64);
                Cb = Ca * wB + Cb;
                Ca = Ca * wA;
                look -= 64;
                consumed = true;
            }
            if (!consumed) __builtin_amdgcn_s_sleep(2);
        }
        if (lane == 0) {
            sYin = yin;
            __hip_atomic_store(&Incl[vb], At * yin + Bt, __ATOMIC_RELAXED, SCOPE_AGENT);
            __hip_atomic_store(&flags[vb], 2, __ATOMIC_RELEASE, SCOPE_AGENT);
        }
    }
    __syncthreads();
    const float yin = sYin;

    // ---- in-block tail correction: only past the block's last terminal ----
    if (yin != 0.f) {
        const long long hi = min(lo + (long long)TILE, T) - 1;
        const long long start = (long long)max(lt, (int)lo - 1) + 1;
        for (long long i = start + t; i <= hi; i += TPB) {
            float d = (float)(int)(hi + 1 - i);
            out[i] += exp2f(d * L2DISC) * yin;
        }
    }
}

extern "C" void kernel_launch(void* const* d_in, const int* in_sizes, int n_in,
                              void* d_out, int out_size, void* d_ws, size_t ws_size,
                              hipStream_t stream) {
    const int*   term = (const int*)d_in[0];
    const float* rew  = (const float*)d_in[1];
    float*       out  = (float*)d_out;

    const long long T = (long long)in_sizes[1];
    const int nB = (int)((T + TILE - 1) / TILE);          // 2048 for T=2^24

    // ws layout: [flags nB][ticket 1] | pad16 | [AB nB x u64] [Incl nB x f32]
    int* flags  = (int*)d_ws;
    int* ticket = flags + nB;
    size_t off = (((size_t)(nB + 1) * 4) + 15) & ~(size_t)15;
    unsigned long long* AB = (unsigned long long*)((char*)d_ws + off);
    float* Incl = (float*)(AB + nB);

    (void)hipMemsetAsync(d_ws, 0, (size_t)(nB + 1) * 4, stream);  // flags + ticket
    k_scan<<<nB, TPB, 0, stream>>>(term, rew, out, flags, ticket, AB, Incl, nB, T);
}

// Round 3
// 178.326 us; speedup vs baseline: 2.6249x; 2.6249x over previous
//
#include <hip/hip_runtime.h>

// Discounted cumulative return y[t] = r[t] + a[t]*y[t+1], a[t]=terminal[t]?0:0.99
// Round 10: REVERT the fused decoupled-lookback (R9: 468us — agent-scope
// acquire/release on gfx950 forces cross-XCD L2 inv/writeback storms; WRITE_SIZE
// +42MB, BW collapsed to 0.48 TB/s). Back to the proven two-kernel R7 structure
// (179us) with ONE change in k_local: issue ALL 4 chunks' global loads at block
// start (16x16B per thread, ~64 VGPRs of staged data) so the block's entire
// read traffic is one un-gated burst; compute then runs from registers.
// Also: sWA/sLast double-buffered by chunk parity -> 1 barrier/chunk (was 2).
//
//   K1: in-block scan with y_in=0 -> out, per-block aggregate (A,B) + last
//       terminal index. Inputs read once.
//   K2: per-block compose of aggregates above -> y_in; correction
//       out[i] += 0.99^(hi+1-i) * y_in only past the block's last terminal.
//
// Affine F(x)=A*x+B maps y[hi+1]->y[lo]; compose outer = lower indices:
// (A1,B1)o(A2,B2) = (A1*A2, A1*B2+B1).

constexpr int   TPB   = 256;
constexpr int   IPTC  = 8;               // elems per thread per chunk
constexpr int   NCH   = 4;               // chunks per block
constexpr int   CHUNK = TPB * IPTC;      // 2048
constexpr int   TILE  = CHUNK * NCH;     // 8192 elems per block
constexpr float DISC  = 0.99f;
constexpr float L2DISC = -0.0144995696f; // log2(0.99)

// Inclusive wave SUFFIX scan: lane l ends with F_l o F_{l+1} o ... o F_63.
__device__ __forceinline__ void wave_suffix_scan(float& A, float& B, int lane) {
    #pragma unroll
    for (int off = 1; off < 64; off <<= 1) {
        float oA = __shfl_down(A, off, 64);
        float oB = __shfl_down(B, off, 64);
        if (lane + off < 64) { B = A * oB + B; A = A * oA; }
    }
}

// K1: local scan (y_in = 0) -> out; write agg[b] and lastT[b].
__global__ __launch_bounds__(TPB) void k_local(
        const int* __restrict__ term, const float* __restrict__ rew,
        float* __restrict__ out, float2* __restrict__ agg,
        int* __restrict__ lastT, long long T) {
    __shared__ float2 sWA[2][TPB / 64];
    __shared__ int    sLast[2][TPB / 64];

    const int t = threadIdx.x;
    const int lane = t & 63, wav = t >> 6;
    const int b = blockIdx.x;
    const long long lo = (long long)b * TILE;
    const bool fastblk = (lo + TILE <= T);

    float At = 1.f, Bt = 0.f;   // block aggregate over processed (higher) chunks
    int   lt = -1;              // last terminal global index in block

    if (fastblk) {
        float4 bR[NCH][IPTC / 4];
        int4   bT[NCH][IPTC / 4];

        // Issue ALL chunk loads up front, highest chunk first (it's consumed
        // first, so its vmcnt drains earliest). One big burst per block; no
        // load is gated behind a barrier or a compute chain.
        #pragma unroll
        for (int c = NCH - 1; c >= 0; --c) {
            const long long base = lo + (long long)c * CHUNK + (long long)t * IPTC;
            const float4* rp = (const float4*)(rew + base);
            const int4*   tp = (const int4*)(term + base);
            #pragma unroll
            for (int q = 0; q < IPTC / 4; ++q) {
                bR[c][q] = rp[q];
                bT[c][q] = tp[q];
            }
        }

        #pragma unroll
        for (int c = NCH - 1; c >= 0; --c) {
            const int pb = c & 1;                 // LDS buffer parity
            const long long base = lo + (long long)c * CHUNK + (long long)t * IPTC;

            float r[IPTC];
            unsigned mask = 0;
            #pragma unroll
            for (int q = 0; q < IPTC / 4; ++q) {
                float4 rv = bR[c][q];
                int4   tv = bT[c][q];
                r[4*q+0] = rv.x; r[4*q+1] = rv.y; r[4*q+2] = rv.z; r[4*q+3] = rv.w;
                mask |= (tv.x ? 1u : 0u) << (4*q+0);
                mask |= (tv.y ? 1u : 0u) << (4*q+1);
                mask |= (tv.z ? 1u : 0u) << (4*q+2);
                mask |= (tv.w ? 1u : 0u) << (4*q+3);
            }

            // thread-local compose, high->low
            float A = 1.f, B = 0.f;
            #pragma unroll
            for (int k = IPTC - 1; k >= 0; --k) {
                float ak = ((mask >> k) & 1u) ? 0.f : DISC;
                B = ak * B + r[k]; A = ak * A;
            }

            float IA = A, IB = B;
            wave_suffix_scan(IA, IB, lane);

            int myLast = mask ? (int)(base + (31 - __clz(mask))) : -1;
            #pragma unroll
            for (int off = 32; off > 0; off >>= 1)
                myLast = max(myLast, __shfl_down(myLast, off, 64));

            if (lane == 0) { sWA[pb][wav] = make_float2(IA, IB); sLast[pb][wav] = myLast; }
            __syncthreads();
            // No trailing barrier needed: next chunk writes the OTHER parity
            // buffer, and a wave only reaches that write after this barrier,
            // by which point every wave has finished reading that buffer
            // (its reads happened before the PREVIOUS barrier).

            // chunk aggregate + exclusives (all threads, redundant & cheap)
            float2 g = sWA[pb][0];
            int cl = sLast[pb][0];
            #pragma unroll
            for (int w = 1; w < TPB / 64; ++w) {
                float2 h = sWA[pb][w];
                g.y = g.x * h.y + g.y; g.x = g.x * h.x;
                cl = max(cl, sLast[pb][w]);
            }
            float EWA = 1.f, EWB = 0.f;
            #pragma unroll
            for (int w = 0; w < TPB / 64; ++w)
                if (w > wav) { float2 h = sWA[pb][w]; EWB = EWA*h.y + EWB; EWA = EWA*h.x; }

            float EA = __shfl_down(IA, 1, 64);
            float EB = __shfl_down(IB, 1, 64);
            if (lane == 63) { EA = 1.f; EB = 0.f; }

            const float Yc = Bt;              // y entering this chunk from above
            float y = EA * (EWA * Yc + EWB) + EB;

            #pragma unroll
            for (int k = IPTC - 1; k >= 0; --k) {
                float ak = ((mask >> k) & 1u) ? 0.f : DISC;
                y = ak * y + r[k]; r[k] = y;
            }

            float4* op = (float4*)(out + base);
            #pragma unroll
            for (int q = 0; q < IPTC / 4; ++q)
                op[q] = make_float4(r[4*q+0], r[4*q+1], r[4*q+2], r[4*q+3]);

            // fold chunk into block aggregate: F_new = F_c o F_prev
            Bt = g.x * Bt + g.y;
            At = g.x * At;
            lt = max(lt, cl);
        }
    } else {
        // guarded tail block (only the last block when T % TILE != 0)
        for (int c = NCH - 1; c >= 0; --c) {
            const int pb = c & 1;
            const long long base = lo + (long long)c * CHUNK + (long long)t * IPTC;
            float r[IPTC];
            unsigned mask = 0;
            #pragma unroll
            for (int k = 0; k < IPTC; ++k) {
                long long i = base + k;
                if (i < T) { r[k] = rew[i]; mask |= (term[i] ? 1u : 0u) << k; }
                else       { r[k] = 0.f; }
            }
            float A = 1.f, B = 0.f;
            #pragma unroll
            for (int k = IPTC - 1; k >= 0; --k) {
                float ak = ((mask >> k) & 1u) ? 0.f : DISC;
                if (base + k >= T) ak = 1.f;
                B = ak * B + r[k]; A = ak * A;
            }
            float IA = A, IB = B;
            wave_suffix_scan(IA, IB, lane);

            int myLast = mask ? (int)(base + (31 - __clz(mask))) : -1;
            #pragma unroll
            for (int off = 32; off > 0; off >>= 1)
                myLast = max(myLast, __shfl_down(myLast, off, 64));

            if (lane == 0) { sWA[pb][wav] = make_float2(IA, IB); sLast[pb][wav] = myLast; }
            __syncthreads();

            float2 g = sWA[pb][0];
            int cl = sLast[pb][0];
            #pragma unroll
            for (int w = 1; w < TPB / 64; ++w) {
                float2 h = sWA[pb][w];
                g.y = g.x * h.y + g.y; g.x = g.x * h.x;
                cl = max(cl, sLast[pb][w]);
            }
            float EWA = 1.f, EWB = 0.f;
            #pragma unroll
            for (int w = 0; w < TPB / 64; ++w)
                if (w > wav) { float2 h = sWA[pb][w]; EWB = EWA*h.y + EWB; EWA = EWA*h.x; }

            float EA = __shfl_down(IA, 1, 64);
            float EB = __shfl_down(IB, 1, 64);
            if (lane == 63) { EA = 1.f; EB = 0.f; }

            const float Yc = Bt;
            float y = EA * (EWA * Yc + EWB) + EB;

            #pragma unroll
            for (int k = IPTC - 1; k >= 0; --k) {
                float ak = ((mask >> k) & 1u) ? 0.f : DISC;
                if (base + k >= T) ak = 1.f;
                y = ak * y + r[k]; r[k] = y;
            }
            #pragma unroll
            for (int k = 0; k < IPTC; ++k) {
                long long i = base + k;
                if (i < T) out[i] = r[k];
            }

            Bt = g.x * Bt + g.y;
            At = g.x * At;
            lt = max(lt, cl);
        }
    }

    if (t == 0) {
        agg[b] = make_float2(At, Bt);
        lastT[b] = max(lt, (int)lo - 1);   // lo-1 == "no terminal in block"
    }
}

// K2: per-block y_in from aggregates above, then sparse tail correction.
__global__ __launch_bounds__(TPB) void k_fix(
        const float2* __restrict__ agg, const int* __restrict__ lastT,
        float* __restrict__ out, int numBlocks, long long T) {
    __shared__ float2 sWB[TPB / 64];

    const int t = threadIdx.x;
    const int lane = t & 63, wav = t >> 6;
    const int b = blockIdx.x;

    const int cpt = (numBlocks + TPB - 1) / TPB;     // 8 for 2048
    float VA = 1.f, VB = 0.f;
    #pragma unroll
    for (int k = cpt - 1; k >= 0; --k) {             // descending g: inner first
        int g = t * cpt + k;
        if (g > b && g < numBlocks) {
            float2 q = agg[g];
            VB = q.x * VB + q.y; VA = q.x * VA;
        }
    }
    wave_suffix_scan(VA, VB, lane);
    if (lane == 0) sWB[wav] = make_float2(VA, VB);
    __syncthreads();

    float FA = sWB[0].x, FB = sWB[0].y;              // wave 0 outermost
    #pragma unroll
    for (int w = 1; w < TPB / 64; ++w) {
        float2 h = sWB[w];
        FB = FA * h.y + FB; FA = FA * h.x;
    }
    const float yin = FB;                            // y entering block b (x=0)
    if (yin == 0.f) return;

    const long long lo = (long long)b * TILE;
    const long long hi = min(lo + TILE, T) - 1;
    const long long start = (long long)lastT[b] + 1; // >= lo by construction

    for (long long i = start + t; i <= hi; i += TPB) {
        float d = (float)(int)(hi + 1 - i);
        out[i] += exp2f(d * L2DISC) * yin;
    }
}

extern "C" void kernel_launch(void* const* d_in, const int* in_sizes, int n_in,
                              void* d_out, int out_size, void* d_ws, size_t ws_size,
                              hipStream_t stream) {
    const int*   term = (const int*)d_in[0];
    const float* rew  = (const float*)d_in[1];
    float*       out  = (float*)d_out;

    const long long T = (long long)in_sizes[1];
    const int numBlocks = (int)((T + TILE - 1) / TILE);   // 2048 for T=2^24

    float2* agg   = (float2*)d_ws;
    int*    lastT = (int*)(agg + numBlocks);

    k_local<<<numBlocks, TPB, 0, stream>>>(term, rew, out, agg, lastT, T);
    k_fix  <<<numBlocks, TPB, 0, stream>>>(agg, lastT, out, numBlocks, T);
}